// Round 6
// baseline (2692.388 us; speedup 1.0000x reference)
//
#include <hip/hip_runtime.h>
#include <math.h>

#define BT 256
#define LT 256
#define KT 128
#define HT 256
#define LOSS_IDX ((size_t)BT*LT*KT)
#define PRED_IDX (LOSS_IDX + 1)
#define LDP 1280   // P row: [gammah 256 | alpha 128 | gipre 768 | zpre 128] f16
#define GH0 0
#define AL0 256
#define GI0 384
#define ZP0 1152

typedef _Float16 h2 __attribute__((ext_vector_type(2)));
typedef _Float16 f16x8 __attribute__((ext_vector_type(8)));
typedef float f32x4 __attribute__((ext_vector_type(4)));

__device__ __forceinline__ float fd2(h2 a, h2 b, float c){
#if __has_builtin(__builtin_amdgcn_fdot2)
  return __builtin_amdgcn_fdot2(a, b, c, false);
#else
  return c + (float)a[0]*(float)b[0] + (float)a[1]*(float)b[1];
#endif
}
__device__ __forceinline__ h2 lo2(f16x8 v){ return __builtin_shufflevector(v,v,0,1); }
__device__ __forceinline__ h2 p1(f16x8 v){ return __builtin_shufflevector(v,v,2,3); }
__device__ __forceinline__ h2 p2(f16x8 v){ return __builtin_shufflevector(v,v,4,5); }
__device__ __forceinline__ h2 p3(f16x8 v){ return __builtin_shufflevector(v,v,6,7); }
__device__ __forceinline__ float sigf(float v){ return 1.0f/(1.0f + __expf(-v)); }
__device__ __forceinline__ float tanh_fast(float v){
  float a = fminf(fabsf(v), 15.0f);
  float e2 = __expf(2.0f*a);
  float r = (e2 - 1.0f)/(e2 + 1.0f);
  return copysignf(r, v);
}
__device__ __forceinline__ float f16bits(unsigned u, int hi){
  union { unsigned short s; _Float16 h; } c;
  c.s = (unsigned short)(hi ? (u >> 16) : (u & 0xffff));
  return (float)c.h;
}

// ---------- packing kernels ----------
__global__ void pack_cast(const float* __restrict__ src, _Float16* __restrict__ dst,
                          int J, int Kd, int diag, int total){
  int idx = blockIdx.x*256 + threadIdx.x;
  if (idx >= total) return;
  float v = src[idx];
  if (diag && (idx / Kd) == (idx % Kd)) v = 0.0f;
  dst[idx] = (_Float16)v;
}
__global__ void pack_rowchunks(const float* __restrict__ src, _Float16* __restrict__ dst,
                               int J, int K, int total){
  int idx = blockIdx.x*256 + threadIdx.x;
  if (idx >= total) return;
  int j = idx % J, c = idx / J;
  #pragma unroll
  for (int e = 0; e < 8; ++e)
    dst[(size_t)idx*8 + e] = (_Float16)src[(size_t)j*K + c*8 + e];
}
__global__ void pack_col(const float* __restrict__ src, _Float16* __restrict__ dst,
                         int J, int Kc, int ld, int diag, int total){
  int idx = blockIdx.x*256 + threadIdx.x;
  if (idx >= total) return;
  int j = idx % J, k = idx / J;
  float v = src[(size_t)j*ld + k];
  if (diag && j == k) v = 0.0f;
  dst[idx] = (_Float16)v;
}

// ---------- scan: deltas + GEMM inputs ----------
__global__ __launch_bounds__(128) void scan_kernel(
    const float* __restrict__ x, const float* __restrict__ mask, const float* __restrict__ ts,
    const float* __restrict__ W_gx, const float* __restrict__ b_gx,
    const int* __restrict__ record_num,
    _Float16* __restrict__ deltas, _Float16* __restrict__ Agx, _Float16* __restrict__ U)
{
  int b = blockIdx.x, k = threadIdx.x;
  int rn = record_num[b];
  float gxd = W_gx[(size_t)k*KT + k];
  float bgx = b_gx[k];
  float d = 1.0f, tsp = 0.0f;
  for (int t0 = 0; t0 < LT; t0 += 8){
    float xv[8], mv[8], tsv[8];
    #pragma unroll
    for (int u = 0; u < 8; ++u){
      size_t off = ((size_t)b*LT + t0 + u)*KT + k;
      xv[u] = x[off]; mv[u] = mask[off];
      tsv[u] = ts[(size_t)b*LT + t0 + u];
    }
    #pragma unroll
    for (int u = 0; u < 8; ++u){
      int t = t0 + u;
      if (t > 0){
        float gap = fabsf(tsv[u] - (u ? tsv[u-1] : tsp));
        d = gap + (1.0f - mv[u])*d;
      }
      float e = (t < rn) ? 1.0f : 0.0f;
      float dev = d * e;
      size_t row = (size_t)b*LT + t;
      deltas[row*KT + k] = (_Float16)dev;
      float gx = __expf(-fmaxf(fmaf(dev, gxd, bgx), 0.0f));
      Agx[row*2*KT + k]      = (_Float16)gx;
      Agx[row*2*KT + KT + k] = (_Float16)mv[u];
      U[row*2*KT + k]        = (_Float16)(mv[u]*xv[u]);
      U[row*2*KT + KT + k]   = (_Float16)mv[u];
    }
    tsp = tsv[7];
  }
}

__global__ void msum_kernel(const float* __restrict__ mask, float* __restrict__ msumInv){
  __shared__ float red[256];
  int t = blockIdx.x;
  float acc = 0.0f;
  for (int i = threadIdx.x; i < BT*KT; i += 256){
    int b = i >> 7, k = i & 127;
    acc += mask[((size_t)b*LT + t)*KT + k];
  }
  red[threadIdx.x] = acc; __syncthreads();
  for (int s = 128; s > 0; s >>= 1){
    if (threadIdx.x < s) red[threadIdx.x] += red[threadIdx.x + s];
    __syncthreads();
  }
  if (threadIdx.x == 0) msumInv[t] = 1.0f/(red[0] + 1e-5f);
}

// ---------- MFMA GEMM ----------
__global__ __launch_bounds__(256) void gemm_f16(
    const _Float16* __restrict__ A, long ldA, int K,
    const _Float16* __restrict__ B, long ldB,
    _Float16* __restrict__ C, long colofs,
    const float* __restrict__ bias, int op)
{
  const int w = threadIdx.x >> 6, lane = threadIdx.x & 63;
  const int ml = lane & 15, quad = lane >> 4;
  const long m0 = (long)blockIdx.x*64 + w*16;
  const long nb0 = (long)blockIdx.y*64;
  f32x4 acc[4] = {{0,0,0,0},{0,0,0,0},{0,0,0,0},{0,0,0,0}};
  for (int kc = 0; kc < K; kc += 32){
    f16x8 a = *(const f16x8*)(A + (m0 + ml)*ldA + kc + quad*8);
    #pragma unroll
    for (int nt = 0; nt < 4; ++nt){
      f16x8 bfr = *(const f16x8*)(B + (nb0 + nt*16 + ml)*ldB + kc + quad*8);
      acc[nt] = __builtin_amdgcn_mfma_f32_16x16x32_f16(a, bfr, acc[nt], 0, 0, 0);
    }
  }
  #pragma unroll
  for (int nt = 0; nt < 4; ++nt){
    long col = nb0 + nt*16 + ml;
    float bv = (op >= 1) ? bias[col] : 0.0f;
    #pragma unroll
    for (int r = 0; r < 4; ++r){
      float v = acc[nt][r];
      if (op >= 1) v += bv;
      if (op == 2) v = __expf(-fmaxf(v, 0.0f));
      long row = m0 + quad*4 + r;
      C[row*LDP + colofs + col] = (_Float16)v;
    }
  }
}

// ---------- sequential recurrence: 1 block per batch ----------
#define NT 1024

struct __align__(16) SeqS {
  f16x8 whist_l[32*128];        // 64 KB [c*128 + j]
  _Float16 wfc_l[128*128];      // 32 KB [k*128 + j]
  float h[HT];
  float hs[HT];
  alignas(16) _Float16 hsh[HT];
  float gh[3*HT];
  float gi[3*HT];
  float xh[KT];
  float v3[136];
  alignas(4) _Float16 v5h[136];
  int lidx[136];
  int posk[KT];
  int cnt;
  unsigned gam[2][128];         // gamma_h dwords (P dwords 0..127)
  unsigned pbd[2][512];         // P dwords 128..639 (alpha|gi|zp)
  float xb[2][KT], mb[2][KT];
  float bhist[KT], bfeat[KT];
  float bhh[3*HT];
  float wout[HT];
  float minv[LT];
  float red[NT/64];
};

__global__ __launch_bounds__(NT, 1) void rits_seq(
    const float* __restrict__ x, const float* __restrict__ mask,
    const int* __restrict__ record_num, const float* __restrict__ msumInv,
    const _Float16* __restrict__ P,
    const f16x8* __restrict__ Whh_p, const f16x8* __restrict__ Whist_p,
    const _Float16* __restrict__ Wfc, const _Float16* __restrict__ Wihc,
    const float* __restrict__ b_hist, const float* __restrict__ b_feat,
    const float* __restrict__ b_hh,
    const float* __restrict__ W_out, const float* __restrict__ b_out,
    float* __restrict__ out)
{
  __shared__ SeqS s;
  const int tid = threadIdx.x;
  const int b = blockIdx.x;
  const int rn = record_num[b];
  const unsigned* __restrict__ Pd = (const unsigned*)P + (size_t)b*LT*(LDP/2);

  // ---- init ----
  for (int i = tid; i < 32*128; i += NT) s.whist_l[i] = Whist_p[i];
  for (int i = tid; i < 128*128/2; i += NT)
    ((unsigned*)s.wfc_l)[i] = ((const unsigned*)Wfc)[i];
  if (tid < HT){ s.h[tid] = 0.0f; s.hs[tid] = 0.0f; s.hsh[tid] = (_Float16)0.0f; }
  if (tid < KT){ s.bhist[tid] = b_hist[tid]; s.bfeat[tid] = b_feat[tid]; }
  if (tid < 3*HT) s.bhh[tid] = b_hh[tid];
  if (tid < 136) s.lidx[tid] = 0;
  if (tid >= 768 && tid < 768 + HT) s.wout[tid - 768] = W_out[tid - 768];
  if (tid >= 512 && tid < 512 + LT) s.minv[tid - 512] = msumInv[tid - 512];
  if (tid == 0) s.cnt = 0;
  // t=0 stream
  if (tid < 128) s.gam[0][tid] = Pd[tid];
  if (tid >= 256 && tid < 768) s.pbd[0][tid - 256] = Pd[128 + tid - 256];
  if (tid >= 896){
    int k = tid - 896;
    s.xb[0][k] = x[((size_t)b*LT)*KT + k];
    s.mb[0][k] = mask[((size_t)b*LT)*KT + k];
  }
  __syncthreads();

  float loss = 0.0f;
  unsigned pr[5]; float prx = 0.0f, prm = 0.0f;
  h2 wpre[16];

  for (int t = 0; t < LT; ++t){
    const int cur = t & 1, nxt = cur ^ 1;
    const int last = (t == LT - 1);

    // ================= A =================
    if (tid < 768){
      const f16x8* hp = (const f16x8*)s.hsh;
      float a0=0.f, a1=0.f, a2=0.f, a3=0.f;
      #pragma unroll
      for (int c = 0; c < 32; ++c){
        f16x8 w = Whh_p[c*768 + tid];
        f16x8 av = hp[c];
        a0 = fd2(lo2(w), lo2(av), a0);
        a1 = fd2(p1(w),  p1(av),  a1);
        a2 = fd2(p2(w),  p2(av),  a2);
        a3 = fd2(p3(w),  p3(av),  a3);
      }
      s.gh[tid] = (a0 + a1) + (a2 + a3);
    } else if (tid < 896){
      const int j = tid - 768;
      const f16x8* hp = (const f16x8*)s.hsh;
      float a0=0.f, a1=0.f, a2=0.f, a3=0.f;
      #pragma unroll
      for (int c = 0; c < 32; ++c){
        f16x8 w = s.whist_l[c*128 + j];
        f16x8 av = hp[c];
        a0 = fd2(lo2(w), lo2(av), a0);
        a1 = fd2(p1(w),  p1(av),  a1);
        a2 = fd2(p2(w),  p2(av),  a2);
        a3 = fd2(p3(w),  p3(av),  a3);
      }
      float xh = (a0 + a1) + (a2 + a3) + s.bhist[j];
      s.xh[j] = xh;
      float mv = s.mb[cur][j], xv = s.xb[cur][j];
      loss += fabsf(xv - xh) * mv * s.minv[t];
      // ballot-rank list build (order arbitrary, values order-free)
      bool miss = (mv == 0.0f);
      unsigned long long bal = __ballot(miss);
      int lane = tid & 63;
      int rank = __popcll(bal & ((1ull << lane) - 1ull));
      int wcnt = __popcll(bal);
      int base = 0;
      if (lane == 0 && wcnt) base = atomicAdd(&s.cnt, wcnt);
      base = __shfl(base, 0);
      if (miss){
        int pp = base + rank;
        s.lidx[pp] = j; s.v3[pp] = xh; s.posk[j] = pp;
      }
    } else {
      // prefetch next-step streams
      if (!last){
        int i = tid - 896;
        const unsigned* Pn = Pd + (size_t)(t + 1)*(LDP/2);
        #pragma unroll
        for (int u = 0; u < 5; ++u) pr[u] = Pn[u*128 + i];
        size_t offx = ((size_t)b*LT + t + 1)*KT + i;
        prx = x[offx]; prm = mask[offx];
      }
    }
    __syncthreads();   // B1

    // ================= CD =================
    const int c0 = s.cnt;
    if (tid < 768){
      #pragma unroll
      for (int u = 0; u < 16; ++u){
        h2 w;
        w[0] = Wihc[(size_t)s.lidx[2*u]*768 + tid];
        w[1] = Wihc[(size_t)s.lidx[2*u + 1]*768 + tid];
        wpre[u] = w;
      }
    }
    if (tid < KT){
      const int j = tid;
      float za = 0.0f, zb = 0.0f;
      int i = 0;
      for (; i + 1 < c0; i += 2){
        za += s.v3[i]     * (float)s.wfc_l[s.lidx[i]*128 + j];
        zb += s.v3[i + 1] * (float)s.wfc_l[s.lidx[i + 1]*128 + j];
      }
      if (i < c0) za += s.v3[i] * (float)s.wfc_l[s.lidx[i]*128 + j];
      float z = f16bits(s.pbd[cur][448 + (j >> 1)], j & 1) + s.bfeat[j] + za + zb;
      float al = f16bits(s.pbd[cur][j >> 1], j & 1);
      float xh = s.xh[j];
      float mv = s.mb[cur][j], xv = s.xb[cur][j];
      float e = (t < rn) ? 1.0f : 0.0f;
      float inv = s.minv[t];
      float ch = al*z + (1.0f - al)*xh;
      loss += (fabsf(xv - z) + fabsf(xv - ch)) * mv * e * inv;
      float cc = mv*xv + (1.0f - mv)*ch;
      out[((size_t)b*LT + t)*KT + j] = cc * e;
      if (mv == 0.0f) s.v5h[s.posk[j]] = (_Float16)ch;
    } else if (tid < 168){
      int i2 = c0 + (tid - 128);
      if (i2 < 136) s.v5h[i2] = (_Float16)0.0f;
    }
    if (tid >= 896 && !last) s.gam[nxt][tid - 896] = pr[0];
    __syncthreads();   // B2

    // ================= E =================
    if (tid < 768){
      float g  = f16bits(s.pbd[cur][64 + (tid >> 1)], tid & 1);
      float g2 = 0.0f;
      const h2* v5p = (const h2*)s.v5h;
      #pragma unroll
      for (int u = 0; u < 16; u += 2){
        g  = fd2(wpre[u],     v5p[u],     g);
        g2 = fd2(wpre[u + 1], v5p[u + 1], g2);
      }
      for (int i = 32; i < c0; ++i)
        g2 += (float)s.v5h[i] * (float)Wihc[(size_t)s.lidx[i]*768 + tid];
      s.gi[tid] = g + g2;
    }
    __syncthreads();   // B3

    // ================= F =================
    if (tid < HT){
      const int j = tid;
      float ir = s.gi[j], iz = s.gi[HT + j], ig = s.gi[2*HT + j];
      float hr = s.gh[j] + s.bhh[j];
      float hz = s.gh[HT + j] + s.bhh[HT + j];
      float hg = s.gh[2*HT + j] + s.bhh[2*HT + j];
      float r = sigf(ir + hr);
      float zg = sigf(iz + hz);
      float n = tanh_fast(ig + r*hg);
      float hscur = s.hs[j];
      float hn = (1.0f - zg)*n + zg*hscur;
      float he = (t < rn) ? hn : s.h[j];
      s.h[j] = he;
      if (!last){
        float gn = f16bits(s.gam[nxt][j >> 1], j & 1);
        float hsn = he * gn;
        s.hs[j] = hsn;
        s.hsh[j] = (_Float16)hsn;
      }
    }
    if (tid == HT) s.cnt = 0;
    if (tid >= 896 && !last){
      int i = tid - 896;
      #pragma unroll
      for (int u = 1; u < 5; ++u) s.pbd[nxt][(u - 1)*128 + i] = pr[u];
      s.xb[nxt][i] = prx; s.mb[nxt][i] = prm;
    }
    __syncthreads();   // B4
  }

  // ---- loss reduction ----
  #pragma unroll
  for (int off = 32; off; off >>= 1) loss += __shfl_down(loss, off);
  if ((tid & 63) == 0) s.red[tid >> 6] = loss;
  __syncthreads();
  if (tid == 0){
    float tot = 0.0f;
    #pragma unroll
    for (int w = 0; w < NT/64; ++w) tot += s.red[w];
    atomicAdd(&out[LOSS_IDX], tot);
  }

  // ---- prediction ----
  if (tid < HT) s.gh[tid] = s.h[tid] * s.wout[tid];
  __syncthreads();
  for (int st2 = 128; st2 > 0; st2 >>= 1){
    if (tid < st2) s.gh[tid] += s.gh[tid + st2];
    __syncthreads();
  }
  if (tid == 0) out[PRED_IDX + b] = sigf(s.gh[0] + b_out[0]);
}

extern "C" void kernel_launch(void* const* d_in, const int* in_sizes, int n_in,
                              void* d_out, int out_size, void* d_ws, size_t ws_size,
                              hipStream_t stream){
  const float* x      = (const float*)d_in[0];
  const float* mask   = (const float*)d_in[1];
  const float* ts     = (const float*)d_in[2];
  const float* W_gh   = (const float*)d_in[3];
  const float* b_gh   = (const float*)d_in[4];
  const float* W_gx   = (const float*)d_in[5];
  const float* b_gx   = (const float*)d_in[6];
  const float* W_hist = (const float*)d_in[7];
  const float* b_hist = (const float*)d_in[8];
  const float* W_feat = (const float*)d_in[9];
  const float* b_feat = (const float*)d_in[10];
  const float* W_comb = (const float*)d_in[11];
  const float* b_comb = (const float*)d_in[12];
  const float* W_ih   = (const float*)d_in[13];
  const float* W_hh   = (const float*)d_in[14];
  const float* b_ih   = (const float*)d_in[15];
  const float* b_hh   = (const float*)d_in[16];
  const float* W_out  = (const float*)d_in[17];
  const float* b_out  = (const float*)d_in[18];
  const int*   rn     = (const int*)d_in[19];
  float* out = (float*)d_out;
  char* ws = (char*)d_ws;

  size_t off = 0;
  auto alloc = [&](size_t bytes) -> char* {
    char* p = ws + off;
    off += (bytes + 255) & ~(size_t)255;
    return p;
  };
  _Float16* P      = (_Float16*)alloc((size_t)BT*LT*LDP*2);   // 167.8 MB
  _Float16* deltas = (_Float16*)alloc((size_t)BT*LT*KT*2);    // 16.8 MB
  _Float16* Agx    = (_Float16*)alloc((size_t)BT*LT*2*KT*2);  // 33.6 MB
  _Float16* U      = (_Float16*)alloc((size_t)BT*LT*2*KT*2);  // 33.6 MB
  _Float16* WghF   = (_Float16*)alloc(HT*KT*2);
  _Float16* WcombF = (_Float16*)alloc(KT*2*KT*2);
  _Float16* WihF   = (_Float16*)alloc(3*HT*2*KT*2);
  _Float16* WfeatF = (_Float16*)alloc(KT*KT*2);
  _Float16* Whh_p  = (_Float16*)alloc(3*HT*HT*2);
  _Float16* Whist_p= (_Float16*)alloc(KT*HT*2);
  _Float16* Wfc    = (_Float16*)alloc(KT*KT*2);
  _Float16* Wihc   = (_Float16*)alloc(KT*3*HT*2);
  float* msumInv   = (float*)alloc(LT*4);

  auto grid1 = [](int n){ return dim3((n + 255)/256); };
  pack_cast<<<grid1(HT*KT), 256, 0, stream>>>(W_gh, WghF, HT, KT, 0, HT*KT);
  pack_cast<<<grid1(KT*2*KT), 256, 0, stream>>>(W_comb, WcombF, KT, 2*KT, 0, KT*2*KT);
  pack_cast<<<grid1(3*HT*2*KT), 256, 0, stream>>>(W_ih, WihF, 3*HT, 2*KT, 0, 3*HT*2*KT);
  pack_cast<<<grid1(KT*KT), 256, 0, stream>>>(W_feat, WfeatF, KT, KT, 1, KT*KT);
  pack_rowchunks<<<grid1(3*HT*(HT/8)), 256, 0, stream>>>(W_hh, Whh_p, 3*HT, HT, 3*HT*(HT/8));
  pack_rowchunks<<<grid1(KT*(HT/8)), 256, 0, stream>>>(W_hist, Whist_p, KT, HT, KT*(HT/8));
  pack_col<<<grid1(KT*KT), 256, 0, stream>>>(W_feat, Wfc, KT, KT, KT, 1, KT*KT);
  pack_col<<<grid1(768*KT), 256, 0, stream>>>(W_ih, Wihc, 3*HT, KT, 2*KT, 0, 3*HT*KT);

  scan_kernel<<<dim3(BT), dim3(KT), 0, stream>>>(x, mask, ts, W_gx, b_gx, rn, deltas, Agx, U);
  msum_kernel<<<dim3(LT), dim3(256), 0, stream>>>(mask, msumInv);

  const int MR = BT*LT;
  gemm_f16<<<dim3(MR/64, HT/64), 256, 0, stream>>>(deltas, KT, KT, WghF, KT, P, GH0, b_gh, 2);
  gemm_f16<<<dim3(MR/64, KT/64), 256, 0, stream>>>(Agx, 2*KT, 2*KT, WcombF, 2*KT, P, AL0, b_comb, 1);
  gemm_f16<<<dim3(MR/64, 3*HT/64), 256, 0, stream>>>(U, 2*KT, 2*KT, WihF, 2*KT, P, GI0, b_ih, 1);
  gemm_f16<<<dim3(MR/64, KT/64), 256, 0, stream>>>(U, 2*KT, KT, WfeatF, KT, P, ZP0, (const float*)nullptr, 0);

  hipMemsetAsync((void*)(out + LOSS_IDX), 0, sizeof(float), stream);

  rits_seq<<<dim3(BT), dim3(NT), 0, stream>>>(x, mask, rn, msumInv, P,
      (const f16x8*)Whh_p, (const f16x8*)Whist_p, Wfc, Wihc,
      b_hist, b_feat, b_hh, W_out, b_out, out);
}

// Round 7
// 2487.166 us; speedup vs baseline: 1.0825x; 1.0825x over previous
//
#include <hip/hip_runtime.h>
#include <math.h>

#define BT 256
#define LT 256
#define KT 128
#define HT 256
#define LOSS_IDX ((size_t)BT*LT*KT)
#define PRED_IDX (LOSS_IDX + 1)
#define LDP 1280   // P row: [gammah 256 | alpha 128 | gipre 768 | zpre 128] f16
#define GH0 0
#define AL0 256
#define GI0 384
#define ZP0 1152

typedef _Float16 h2 __attribute__((ext_vector_type(2)));
typedef _Float16 f16x8 __attribute__((ext_vector_type(8)));
typedef float f32x4 __attribute__((ext_vector_type(4)));

__device__ __forceinline__ float fd2(h2 a, h2 b, float c){
#if __has_builtin(__builtin_amdgcn_fdot2)
  return __builtin_amdgcn_fdot2(a, b, c, false);
#else
  return c + (float)a[0]*(float)b[0] + (float)a[1]*(float)b[1];
#endif
}
__device__ __forceinline__ h2 lo2(f16x8 v){ return __builtin_shufflevector(v,v,0,1); }
__device__ __forceinline__ h2 p1v(f16x8 v){ return __builtin_shufflevector(v,v,2,3); }
__device__ __forceinline__ h2 p2v(f16x8 v){ return __builtin_shufflevector(v,v,4,5); }
__device__ __forceinline__ h2 p3v(f16x8 v){ return __builtin_shufflevector(v,v,6,7); }
__device__ __forceinline__ float sigf(float v){ return 1.0f/(1.0f + __expf(-v)); }
__device__ __forceinline__ float tanh_fast(float v){
  float a = fminf(fabsf(v), 15.0f);
  float e2 = __expf(2.0f*a);
  float r = (e2 - 1.0f)/(e2 + 1.0f);
  return copysignf(r, v);
}
__device__ __forceinline__ float f16bits(unsigned u, int hi){
  union { unsigned short s; _Float16 h; } c;
  c.s = (unsigned short)(hi ? (u >> 16) : (u & 0xffff));
  return (float)c.h;
}

// ---------- packing kernels ----------
__global__ void pack_cast(const float* __restrict__ src, _Float16* __restrict__ dst,
                          int J, int Kd, int diag, int total){
  int idx = blockIdx.x*256 + threadIdx.x;
  if (idx >= total) return;
  float v = src[idx];
  if (diag && (idx / Kd) == (idx % Kd)) v = 0.0f;
  dst[idx] = (_Float16)v;
}
__global__ void pack_rowchunks(const float* __restrict__ src, _Float16* __restrict__ dst,
                               int J, int K, int total){
  int idx = blockIdx.x*256 + threadIdx.x;
  if (idx >= total) return;
  int j = idx % J, c = idx / J;
  #pragma unroll
  for (int e = 0; e < 8; ++e)
    dst[(size_t)idx*8 + e] = (_Float16)src[(size_t)j*K + c*8 + e];
}
__global__ void pack_col(const float* __restrict__ src, _Float16* __restrict__ dst,
                         int J, int Kc, int ld, int diag, int total){
  int idx = blockIdx.x*256 + threadIdx.x;
  if (idx >= total) return;
  int j = idx % J, k = idx / J;
  float v = src[(size_t)j*ld + k];
  if (diag && j == k) v = 0.0f;
  dst[idx] = (_Float16)v;
}

// ---------- scan: deltas + GEMM inputs ----------
__global__ __launch_bounds__(128) void scan_kernel(
    const float* __restrict__ x, const float* __restrict__ mask, const float* __restrict__ ts,
    const float* __restrict__ W_gx, const float* __restrict__ b_gx,
    const int* __restrict__ record_num,
    _Float16* __restrict__ deltas, _Float16* __restrict__ Agx, _Float16* __restrict__ U)
{
  int b = blockIdx.x, k = threadIdx.x;
  int rn = record_num[b];
  float gxd = W_gx[(size_t)k*KT + k];
  float bgx = b_gx[k];
  float d = 1.0f, tsp = 0.0f;
  for (int t0 = 0; t0 < LT; t0 += 8){
    float xv[8], mv[8], tsv[8];
    #pragma unroll
    for (int u = 0; u < 8; ++u){
      size_t off = ((size_t)b*LT + t0 + u)*KT + k;
      xv[u] = x[off]; mv[u] = mask[off];
      tsv[u] = ts[(size_t)b*LT + t0 + u];
    }
    #pragma unroll
    for (int u = 0; u < 8; ++u){
      int t = t0 + u;
      if (t > 0){
        float gap = fabsf(tsv[u] - (u ? tsv[u-1] : tsp));
        d = gap + (1.0f - mv[u])*d;
      }
      float e = (t < rn) ? 1.0f : 0.0f;
      float dev = d * e;
      size_t row = (size_t)b*LT + t;
      deltas[row*KT + k] = (_Float16)dev;
      float gx = __expf(-fmaxf(fmaf(dev, gxd, bgx), 0.0f));
      Agx[row*2*KT + k]      = (_Float16)gx;
      Agx[row*2*KT + KT + k] = (_Float16)mv[u];
      U[row*2*KT + k]        = (_Float16)(mv[u]*xv[u]);
      U[row*2*KT + KT + k]   = (_Float16)mv[u];
    }
    tsp = tsv[7];
  }
}

__global__ void msum_kernel(const float* __restrict__ mask, float* __restrict__ msumInv){
  __shared__ float red[256];
  int t = blockIdx.x;
  float acc = 0.0f;
  for (int i = threadIdx.x; i < BT*KT; i += 256){
    int b = i >> 7, k = i & 127;
    acc += mask[((size_t)b*LT + t)*KT + k];
  }
  red[threadIdx.x] = acc; __syncthreads();
  for (int s = 128; s > 0; s >>= 1){
    if (threadIdx.x < s) red[threadIdx.x] += red[threadIdx.x + s];
    __syncthreads();
  }
  if (threadIdx.x == 0) msumInv[t] = 1.0f/(red[0] + 1e-5f);
}

// ---------- MFMA GEMM ----------
__global__ __launch_bounds__(256) void gemm_f16(
    const _Float16* __restrict__ A, long ldA, int K,
    const _Float16* __restrict__ B, long ldB,
    _Float16* __restrict__ C, long colofs,
    const float* __restrict__ bias, int op)
{
  const int w = threadIdx.x >> 6, lane = threadIdx.x & 63;
  const int ml = lane & 15, quad = lane >> 4;
  const long m0 = (long)blockIdx.x*64 + w*16;
  const long nb0 = (long)blockIdx.y*64;
  f32x4 acc[4] = {{0,0,0,0},{0,0,0,0},{0,0,0,0},{0,0,0,0}};
  for (int kc = 0; kc < K; kc += 32){
    f16x8 a = *(const f16x8*)(A + (m0 + ml)*ldA + kc + quad*8);
    #pragma unroll
    for (int nt = 0; nt < 4; ++nt){
      f16x8 bfr = *(const f16x8*)(B + (nb0 + nt*16 + ml)*ldB + kc + quad*8);
      acc[nt] = __builtin_amdgcn_mfma_f32_16x16x32_f16(a, bfr, acc[nt], 0, 0, 0);
    }
  }
  #pragma unroll
  for (int nt = 0; nt < 4; ++nt){
    long col = nb0 + nt*16 + ml;
    float bv = (op >= 1) ? bias[col] : 0.0f;
    #pragma unroll
    for (int r = 0; r < 4; ++r){
      float v = acc[nt][r];
      if (op >= 1) v += bv;
      if (op == 2) v = __expf(-fmaxf(v, 0.0f));
      long row = m0 + quad*4 + r;
      C[row*LDP + colofs + col] = (_Float16)v;
    }
  }
}

// ---------- sequential recurrence: 1 block per batch ----------
#define NT 768

struct __align__(16) SeqS {
  f16x8 whist_l[32*128];        // 64 KB [c*128 + j]
  _Float16 wfc_l[128*128];      // 32 KB [k*128 + j]
  float h[HT];
  float hs[HT];
  alignas(16) _Float16 hsh[HT];
  float gh[3*HT];
  float gi[3*HT];
  float xh[KT];
  float part6[6][KT];
  float v3[136];
  alignas(4) _Float16 v5h[136];
  int lidx[136];
  int posk[KT];
  int cnt;
  unsigned pb[2][LDP/2];
  float xb[2][KT], mb[2][KT];
  float bhist[KT], bfeat[KT];
  float bhh[3*HT];
  float wout[HT];
  float minv[LT];
  float red[NT/64];
};

__global__ __launch_bounds__(NT, 1) void rits_seq(
    const float* __restrict__ x, const float* __restrict__ mask,
    const int* __restrict__ record_num, const float* __restrict__ msumInv,
    const _Float16* __restrict__ P,
    const f16x8* __restrict__ Whh_p, const f16x8* __restrict__ Whist_p,
    const _Float16* __restrict__ Wfc, const _Float16* __restrict__ Wihc,
    const float* __restrict__ b_hist, const float* __restrict__ b_feat,
    const float* __restrict__ b_hh,
    const float* __restrict__ W_out, const float* __restrict__ b_out,
    float* __restrict__ out)
{
  __shared__ SeqS s;
  const int tid = threadIdx.x;
  const int b = blockIdx.x;
  const int rn = record_num[b];
  const unsigned* __restrict__ Pd = (const unsigned*)P + (size_t)b*LT*(LDP/2);

  // ---- init: LDS-resident weights + constants ----
  for (int i = tid; i < 32*128; i += NT) s.whist_l[i] = Whist_p[i];
  for (int i = tid; i < 128*128/2; i += NT)
    ((unsigned*)s.wfc_l)[i] = ((const unsigned*)Wfc)[i];
  if (tid < HT) s.h[tid] = 0.0f;
  if (tid < KT){ s.bhist[tid] = b_hist[tid]; s.bfeat[tid] = b_feat[tid]; }
  if (tid < 3*HT) s.bhh[tid] = b_hh[tid];
  if (tid < 136){ s.lidx[tid] = 0; s.v5h[tid] = (_Float16)0.0f; }
  if (tid >= 256 && tid < 512) s.wout[tid - 256] = W_out[tid - 256];
  if (tid >= 512 && tid < 512 + LT) s.minv[tid - 512] = msumInv[tid - 512];
  if (tid == 0) s.cnt = 0;
  // preload t=0 streams
  if (tid < LDP/2) s.pb[0][tid] = Pd[tid];
  else if (tid < LDP/2 + KT){
    int k = tid - LDP/2;
    s.xb[0][k] = x[((size_t)b*LT)*KT + k];
    s.mb[0][k] = mask[((size_t)b*LT)*KT + k];
  }
  __syncthreads();

  float loss = 0.0f;
  h2 wpre[24];

  for (int t = 0; t < LT; ++t){
    const int cur = t & 1, nxt = cur ^ 1;

    // ---- P1: hs = h*gamma_h ; next-step prefetch ; list build from mask(t) ----
    unsigned pr0 = 0; float prx = 0.0f, prm = 0.0f;
    if (t < LT - 1){
      if (tid < LDP/2) pr0 = Pd[(size_t)(t+1)*(LDP/2) + tid];
      else {
        int k = tid - LDP/2;
        size_t offx = ((size_t)b*LT + t + 1)*KT + k;
        prx = x[offx]; prm = mask[offx];
      }
    }
    if (tid < HT){
      float g = f16bits(s.pb[cur][tid >> 1], tid & 1);
      float hsv = s.h[tid] * g;
      s.hs[tid] = hsv;
      s.hsh[tid] = (_Float16)hsv;
    }
    if (tid < KT){
      bool miss = (s.mb[cur][tid] == 0.0f);
      unsigned long long bal = __ballot(miss);
      int lane = tid & 63;
      int rank = __popcll(bal & ((1ull << lane) - 1ull));
      int wcnt = __popcll(bal);
      int base = 0;
      if (lane == 0 && wcnt) base = atomicAdd(&s.cnt, wcnt);
      base = __shfl(base, 0);
      if (miss){
        int pp = base + rank;
        s.lidx[pp] = tid; s.posk[tid] = pp;
      }
    }
    __syncthreads();

    // ---- A: Wihc column prefetch (hidden) + gh (all 768) + xh (tid<128) ----
    {
      // scattered prefetch first: consumed in E, hidden behind A's port traffic
      #pragma unroll
      for (int u = 0; u < 24; ++u){
        h2 w;
        w[0] = Wihc[(size_t)s.lidx[2*u]*768 + tid];
        w[1] = Wihc[(size_t)s.lidx[2*u + 1]*768 + tid];
        wpre[u] = w;
      }
      const f16x8* hp = (const f16x8*)s.hsh;
      if (tid < KT){
        const int j = tid;
        float a0=0.f, a1=0.f, a2=0.f, a3=0.f;
        #pragma unroll 8
        for (int c = 0; c < 32; ++c){
          f16x8 w = s.whist_l[c*128 + j];
          f16x8 av = hp[c];
          a0 = fd2(lo2(w), lo2(av), a0);
          a1 = fd2(p1v(w), p1v(av), a1);
          a2 = fd2(p2v(w), p2v(av), a2);
          a3 = fd2(p3v(w), p3v(av), a3);
        }
        float xh = (a0 + a1) + (a2 + a3) + s.bhist[j];
        s.xh[j] = xh;
        float mv = s.mb[cur][j], xv = s.xb[cur][j];
        loss += fabsf(xv - xh) * mv * s.minv[t];
        if (mv == 0.0f) s.v3[s.posk[j]] = xh;
      }
      float a0=0.f, a1=0.f, a2=0.f, a3=0.f;
      #pragma unroll 8
      for (int c = 0; c < 32; ++c){
        f16x8 w = Whh_p[c*768 + tid];
        f16x8 av = hp[c];
        a0 = fd2(lo2(w), lo2(av), a0);
        a1 = fd2(p1v(w), p1v(av), a1);
        a2 = fd2(p2v(w), p2v(av), a2);
        a3 = fd2(p3v(w), p3v(av), a3);
      }
      s.gh[tid] = (a0 + a1) + (a2 + a3);
    }
    __syncthreads();

    // ---- C: zh strata (6-way parallel, LDS Wfc) ----
    const int c0 = s.cnt;
    {
      int st = tid >> 7, j = tid & 127;
      float a = 0.0f;
      for (int i = st; i < c0; i += 6)
        a += s.v3[i] * (float)s.wfc_l[s.lidx[i]*128 + j];
      s.part6[st][j] = a;
    }
    __syncthreads();

    // ---- D: z_h, c_h, losses, imputation, v5 (tid<128) ----
    if (tid < KT){
      const int j = tid;
      float z = f16bits(s.pb[cur][ZP0/2 + (j >> 1)], j & 1) + s.bfeat[j]
              + s.part6[0][j] + s.part6[1][j] + s.part6[2][j]
              + s.part6[3][j] + s.part6[4][j] + s.part6[5][j];
      float al = f16bits(s.pb[cur][AL0/2 + (j >> 1)], j & 1);
      float xh = s.xh[j];
      float mv = s.mb[cur][j], xv = s.xb[cur][j];
      float e = (t < rn) ? 1.0f : 0.0f;
      float inv = s.minv[t];
      float ch = al*z + (1.0f - al)*xh;
      loss += (fabsf(xv - z) + fabsf(xv - ch)) * mv * e * inv;
      float cc = mv*xv + (1.0f - mv)*ch;
      out[((size_t)b*LT + t)*KT + j] = cc * e;
      if (mv == 0.0f) s.v5h[s.posk[j]] = (_Float16)ch;
    } else if (tid < 192){
      int i2 = c0 + (tid - 128);
      if (i2 < 136) s.v5h[i2] = (_Float16)0.0f;
    }
    __syncthreads();

    // ---- E: sparse M5 -> gi (48-wide prefetched head + rare tail) ----
    {
      float g  = f16bits(s.pb[cur][GI0/2 + (tid >> 1)], tid & 1);
      float g2 = 0.0f;
      const h2* v5p = (const h2*)s.v5h;
      #pragma unroll
      for (int u = 0; u < 24; u += 2){
        g  = fd2(wpre[u],     v5p[u],     g);
        g2 = fd2(wpre[u + 1], v5p[u + 1], g2);
      }
      for (int i = 48; i < c0; ++i)
        g2 += (float)s.v5h[i] * (float)Wihc[(size_t)s.lidx[i]*768 + tid];
      s.gi[tid] = g + g2;
    }
    __syncthreads();

    // ---- F: gates + h update ; stage prefetched buffers ; reset cnt ----
    if (tid < HT){
      const int j = tid;
      float ir = s.gi[j], iz = s.gi[HT + j], ig = s.gi[2*HT + j];
      float hr = s.gh[j] + s.bhh[j];
      float hz = s.gh[HT + j] + s.bhh[HT + j];
      float hg = s.gh[2*HT + j] + s.bhh[2*HT + j];
      float r = sigf(ir + hr);
      float zg = sigf(iz + hz);
      float n = tanh_fast(ig + r*hg);
      float hn = (1.0f - zg)*n + zg*s.hs[j];
      if (t < rn) s.h[j] = hn;
    }
    if (tid == 320) s.cnt = 0;
    if (t < LT - 1){
      if (tid < LDP/2) s.pb[nxt][tid] = pr0;
      else {
        int k = tid - LDP/2;
        s.xb[nxt][k] = prx; s.mb[nxt][k] = prm;
      }
    }
    __syncthreads();
  }

  // ---- loss reduction ----
  #pragma unroll
  for (int off = 32; off; off >>= 1) loss += __shfl_down(loss, off);
  if ((tid & 63) == 0) s.red[tid >> 6] = loss;
  __syncthreads();
  if (tid == 0){
    float tot = 0.0f;
    #pragma unroll
    for (int w = 0; w < NT/64; ++w) tot += s.red[w];
    atomicAdd(&out[LOSS_IDX], tot);
  }

  // ---- prediction ----
  if (tid < HT) s.gh[tid] = s.h[tid] * s.wout[tid];
  __syncthreads();
  for (int st2 = 128; st2 > 0; st2 >>= 1){
    if (tid < st2) s.gh[tid] += s.gh[tid + st2];
    __syncthreads();
  }
  if (tid == 0) out[PRED_IDX + b] = sigf(s.gh[0] + b_out[0]);
}

extern "C" void kernel_launch(void* const* d_in, const int* in_sizes, int n_in,
                              void* d_out, int out_size, void* d_ws, size_t ws_size,
                              hipStream_t stream){
  const float* x      = (const float*)d_in[0];
  const float* mask   = (const float*)d_in[1];
  const float* ts     = (const float*)d_in[2];
  const float* W_gh   = (const float*)d_in[3];
  const float* b_gh   = (const float*)d_in[4];
  const float* W_gx   = (const float*)d_in[5];
  const float* b_gx   = (const float*)d_in[6];
  const float* W_hist = (const float*)d_in[7];
  const float* b_hist = (const float*)d_in[8];
  const float* W_feat = (const float*)d_in[9];
  const float* b_feat = (const float*)d_in[10];
  const float* W_comb = (const float*)d_in[11];
  const float* b_comb = (const float*)d_in[12];
  const float* W_ih   = (const float*)d_in[13];
  const float* W_hh   = (const float*)d_in[14];
  const float* b_ih   = (const float*)d_in[15];
  const float* b_hh   = (const float*)d_in[16];
  const float* W_out  = (const float*)d_in[17];
  const float* b_out  = (const float*)d_in[18];
  const int*   rn     = (const int*)d_in[19];
  float* out = (float*)d_out;
  char* ws = (char*)d_ws;

  size_t off = 0;
  auto alloc = [&](size_t bytes) -> char* {
    char* p = ws + off;
    off += (bytes + 255) & ~(size_t)255;
    return p;
  };
  _Float16* P      = (_Float16*)alloc((size_t)BT*LT*LDP*2);   // 167.8 MB
  _Float16* deltas = (_Float16*)alloc((size_t)BT*LT*KT*2);    // 16.8 MB
  _Float16* Agx    = (_Float16*)alloc((size_t)BT*LT*2*KT*2);  // 33.6 MB
  _Float16* U      = (_Float16*)alloc((size_t)BT*LT*2*KT*2);  // 33.6 MB
  _Float16* WghF   = (_Float16*)alloc(HT*KT*2);
  _Float16* WcombF = (_Float16*)alloc(KT*2*KT*2);
  _Float16* WihF   = (_Float16*)alloc(3*HT*2*KT*2);
  _Float16* WfeatF = (_Float16*)alloc(KT*KT*2);
  _Float16* Whh_p  = (_Float16*)alloc(3*HT*HT*2);
  _Float16* Whist_p= (_Float16*)alloc(KT*HT*2);
  _Float16* Wfc    = (_Float16*)alloc(KT*KT*2);
  _Float16* Wihc   = (_Float16*)alloc(KT*3*HT*2);
  float* msumInv   = (float*)alloc(LT*4);

  auto grid1 = [](int n){ return dim3((n + 255)/256); };
  pack_cast<<<grid1(HT*KT), 256, 0, stream>>>(W_gh, WghF, HT, KT, 0, HT*KT);
  pack_cast<<<grid1(KT*2*KT), 256, 0, stream>>>(W_comb, WcombF, KT, 2*KT, 0, KT*2*KT);
  pack_cast<<<grid1(3*HT*2*KT), 256, 0, stream>>>(W_ih, WihF, 3*HT, 2*KT, 0, 3*HT*2*KT);
  pack_cast<<<grid1(KT*KT), 256, 0, stream>>>(W_feat, WfeatF, KT, KT, 1, KT*KT);
  pack_rowchunks<<<grid1(3*HT*(HT/8)), 256, 0, stream>>>(W_hh, Whh_p, 3*HT, HT, 3*HT*(HT/8));
  pack_rowchunks<<<grid1(KT*(HT/8)), 256, 0, stream>>>(W_hist, Whist_p, KT, HT, KT*(HT/8));
  pack_col<<<grid1(KT*KT), 256, 0, stream>>>(W_feat, Wfc, KT, KT, KT, 1, KT*KT);
  pack_col<<<grid1(768*KT), 256, 0, stream>>>(W_ih, Wihc, 3*HT, KT, 2*KT, 0, 3*HT*KT);

  scan_kernel<<<dim3(BT), dim3(KT), 0, stream>>>(x, mask, ts, W_gx, b_gx, rn, deltas, Agx, U);
  msum_kernel<<<dim3(LT), dim3(256), 0, stream>>>(mask, msumInv);

  const int MR = BT*LT;
  gemm_f16<<<dim3(MR/64, HT/64), 256, 0, stream>>>(deltas, KT, KT, WghF, KT, P, GH0, b_gh, 2);
  gemm_f16<<<dim3(MR/64, KT/64), 256, 0, stream>>>(Agx, 2*KT, 2*KT, WcombF, 2*KT, P, AL0, b_comb, 1);
  gemm_f16<<<dim3(MR/64, 3*HT/64), 256, 0, stream>>>(U, 2*KT, 2*KT, WihF, 2*KT, P, GI0, b_ih, 1);
  gemm_f16<<<dim3(MR/64, KT/64), 256, 0, stream>>>(U, 2*KT, KT, WfeatF, KT, P, ZP0, (const float*)nullptr, 0);

  hipMemsetAsync((void*)(out + LOSS_IDX), 0, sizeof(float), stream);

  rits_seq<<<dim3(BT), dim3(NT), 0, stream>>>(x, mask, rn, msumInv, P,
      (const f16x8*)Whh_p, (const f16x8*)Whist_p, Wfc, Wihc,
      b_hist, b_feat, b_hh, W_out, b_out, out);
}